// Round 10
// baseline (124.064 us; speedup 1.0000x reference)
//
#include <hip/hip_runtime.h>

// x: (128, 55, 55, 96) NHWC fp32; kernel: (96, 5, 5) fp32 depthwise; out = x + dwconv(x,k)
#define NB 128
#define HW 55
#define IMG (HW * HW)            // 3025
#define CH 96
#define GROUPS (CH / 4)          // 24 float4 channel-groups
#define NPAIRS (GROUPS / 2)      // 12 channel-pairs (8 floats each)
#define TAPS 25
#define WSTRIDE CH               // 96 floats
#define HSTRIDE (HW * CH)        // 5280 floats
#define NPIX (NB * IMG)          // 387,200 pixels
#define TOTITEM (NPIX * NPAIRS)  // 4,646,400 pair-items
#define NWG (TOTITEM / 256)      // 18,150 blocks (exact)
#define NXCD 8
#define PSLOTCAP 56              // >= 2*TAPS, multiple of 8

typedef float v4f __attribute__((ext_vector_type(4)));

// ---- workspace layout ----
// float4 wtab[PSLOTCAP*2][NPAIRS] : slot s -> [s*2+0]=wA (low group), [s*2+1]=wB   21504 B
// int2   dtab[PSLOTCAP][NPAIRS]   : {float-offset, (dh+2)<<4 | (dw+2)} (pad: 0/center) 5376 B
// int    ntp[NPAIRS]              : concat slot count per pair
// int    nbmax                    : ceil(max ntp / 8)  (0 if kernel all-zero)

__global__ void repack_kernel(const float* __restrict__ k,
                              float4* __restrict__ wtab,
                              int2* __restrict__ dtab,
                              int* __restrict__ ntp,
                              int* __restrict__ nbmax) {
    int j = threadIdx.x;
    if (j < NPAIRS) {
        int ns = 0;
        // group A = channels 8j..8j+3, group B = channels 8j+4..8j+7
        for (int half = 0; half < 2; ++half) {
            int c0 = 8 * j + 4 * half;
            for (int tap = 0; tap < TAPS; ++tap) {
                float w0 = k[(c0 + 0) * TAPS + tap];
                float w1 = k[(c0 + 1) * TAPS + tap];
                float w2 = k[(c0 + 2) * TAPS + tap];
                float w3 = k[(c0 + 3) * TAPS + tap];
                if (w0 != 0.f || w1 != 0.f || w2 != 0.f || w3 != 0.f) {
                    int dh = tap / 5 - 2, dw = tap % 5 - 2;
                    dtab[ns * NPAIRS + j] =
                        make_int2(dh * HSTRIDE + dw * WSTRIDE, ((dh + 2) << 4) | (dw + 2));
                    float4 wz = make_float4(0.f, 0.f, 0.f, 0.f);
                    float4 wv = make_float4(w0, w1, w2, w3);
                    wtab[(ns * 2 + 0) * NPAIRS + j] = half ? wz : wv;
                    wtab[(ns * 2 + 1) * NPAIRS + j] = half ? wv : wz;
                    ++ns;
                }
            }
        }
        ntp[j] = ns;
        for (int s = ns; s < PSLOTCAP; ++s) {          // pads contribute exactly 0
            dtab[s * NPAIRS + j] = make_int2(0, (2 << 4) | 2);
            wtab[(s * 2 + 0) * NPAIRS + j] = make_float4(0.f, 0.f, 0.f, 0.f);
            wtab[(s * 2 + 1) * NPAIRS + j] = make_float4(0.f, 0.f, 0.f, 0.f);
        }
    }
    __syncthreads();
    if (threadIdx.x == 0) {
        int m = 0;
        for (int jj = 0; jj < NPAIRS; ++jj) m = m > ntp[jj] ? m : ntp[jj];
        *nbmax = (m + 7) / 8;
    }
}

// ---- fused kernel: one channel-pair (32B) per thread, plain HIP ----
__global__ __launch_bounds__(256) void fused_kernel(const float* __restrict__ x,
                                                    const float4* __restrict__ wtab,
                                                    const int2* __restrict__ dtab,
                                                    const int* __restrict__ ntp,
                                                    const int* __restrict__ nbmax,
                                                    float* __restrict__ out) {
    // Bijective chunked XCD swizzle (m204): contiguous grid ranges per XCD.
    const int q = NWG / NXCD, r = NWG % NXCD;     // 2268, 6
    int xcd = blockIdx.x & (NXCD - 1);
    int idx = blockIdx.x >> 3;
    int swz = (xcd < r ? xcd * (q + 1) : r * (q + 1) + (xcd - r) * q) + idx;

    int u = swz * 256 + threadIdx.x;
    int pair = u % NPAIRS;
    int pp = u / NPAIRS;
    int rem = pp % IMG;
    int h = rem / HW;
    int w = rem - h * HW;

    int base = pp * CH + pair * 8;                 // 32B-aligned
    const float* xb = x + base;
    v4f a0 = *reinterpret_cast<const v4f*>(xb);    // residual, low group
    v4f a1 = *reinterpret_cast<const v4f*>(xb + 4);// residual, high group

    const int nt = ntp[pair];
    if (nt > 0) {                                  // ONE exec-masked region
        const int nb = *nbmax;
        for (int b = 0; b < nb; ++b) {
#pragma unroll
            for (int si = 0; si < 8; ++si) {
                const int s = b * 8 + si;
                const int2 d = dtab[s * NPAIRS + pair];
                const int dh2 = d.y >> 4, dw2 = d.y & 15;
                const bool valid = ((unsigned)(h + dh2 - 2) < (unsigned)HW) &
                                   ((unsigned)(w + dw2 - 2) < (unsigned)HW);
                const float sc = valid ? 1.0f : 0.0f;
                const int off = valid ? d.x : 0;
                // both groups share the pixel offset: adjacent 16B+16B loads
                const v4f xv0 = *reinterpret_cast<const v4f*>(xb + off);
                const v4f xv1 = *reinterpret_cast<const v4f*>(xb + off + 4);
                const float4 wa = wtab[(s * 2 + 0) * NPAIRS + pair];
                const float4 wb = wtab[(s * 2 + 1) * NPAIRS + pair];
                a0.x += (wa.x * sc) * xv0.x; a0.y += (wa.y * sc) * xv0.y;
                a0.z += (wa.z * sc) * xv0.z; a0.w += (wa.w * sc) * xv0.w;
                a1.x += (wb.x * sc) * xv1.x; a1.y += (wb.y * sc) * xv1.y;
                a1.z += (wb.z * sc) * xv1.z; a1.w += (wb.w * sc) * xv1.w;
            }
        }
    }
    // contiguous 32B per lane, dense full lines per wave
    __builtin_nontemporal_store(a0, reinterpret_cast<v4f*>(out + base));
    __builtin_nontemporal_store(a1, reinterpret_cast<v4f*>(out + base + 4));
}

// ---- Fallback (ws too small): monolithic, reads raw k — correctness only ----
__global__ __launch_bounds__(256) void fallback_kernel(const float* __restrict__ x,
                                                       const float* __restrict__ kraw,
                                                       float* __restrict__ out) {
    int t = blockIdx.x * 256 + threadIdx.x;
    if (t >= NPIX * GROUPS) return;
    int g = t % GROUPS;
    int pixel = t / GROUPS;
    int rem = pixel % IMG;
    int h = rem / HW;
    int w = rem - h * HW;
    int base = pixel * CH + g * 4;
    const float4 xc = *reinterpret_cast<const float4*>(x + base);
    float4 acc = make_float4(xc.x, xc.y, xc.z, xc.w);
#pragma unroll
    for (int dh = -2; dh <= 2; ++dh)
#pragma unroll
        for (int dw = -2; dw <= 2; ++dw) {
            const int tap = (dh + 2) * 5 + (dw + 2);
            const bool valid = ((unsigned)(h + dh) < (unsigned)HW) &
                               ((unsigned)(w + dw) < (unsigned)HW);
            const float vs = valid ? 1.0f : 0.0f;
            const int off = valid ? (dh * HSTRIDE + dw * WSTRIDE) : 0;
            const float4 xv = *reinterpret_cast<const float4*>(x + base + off);
            acc.x += (kraw[(g * 4 + 0) * TAPS + tap] * vs) * xv.x;
            acc.y += (kraw[(g * 4 + 1) * TAPS + tap] * vs) * xv.y;
            acc.z += (kraw[(g * 4 + 2) * TAPS + tap] * vs) * xv.z;
            acc.w += (kraw[(g * 4 + 3) * TAPS + tap] * vs) * xv.w;
        }
    *reinterpret_cast<float4*>(out + base) = acc;
}

extern "C" void kernel_launch(void* const* d_in, const int* in_sizes, int n_in,
                              void* d_out, int out_size, void* d_ws, size_t ws_size,
                              hipStream_t stream) {
    const float* x = (const float*)d_in[0];
    const float* k = (const float*)d_in[1];
    float* out = (float*)d_out;

    const size_t sz_wtab = (size_t)PSLOTCAP * 2 * NPAIRS * sizeof(float4); // 21504
    const size_t sz_dtab = (size_t)PSLOTCAP * NPAIRS * sizeof(int2);       // 5376
    const size_t sz_ntp = NPAIRS * sizeof(int);
    const size_t ws_need = sz_wtab + sz_dtab + sz_ntp + sizeof(int);

    if (ws_size >= ws_need) {
        char* p = (char*)d_ws;
        float4* wtab = (float4*)p;  p += sz_wtab;
        int2* dtab = (int2*)p;      p += sz_dtab;
        int* ntp = (int*)p;         p += sz_ntp;
        int* nbmax = (int*)p;

        repack_kernel<<<1, 64, 0, stream>>>(k, wtab, dtab, ntp, nbmax);
        fused_kernel<<<NWG, 256, 0, stream>>>(x, wtab, dtab, ntp, nbmax, out);
    } else {
        const int blocks = (NPIX * GROUPS) / 256;
        fallback_kernel<<<blocks, 256, 0, stream>>>(x, k, out);
    }
}

// Round 11
// 97.538 us; speedup vs baseline: 1.2720x; 1.2720x over previous
//
#include <hip/hip_runtime.h>

// x: (128, 55, 55, 96) NHWC fp32; kernel: (96, 5, 5) fp32 depthwise; out = x + dwconv(x,k)
#define NB 128
#define HW 55
#define IMG (HW * HW)            // 3025
#define CH 96
#define GROUPS 24                // float4 channel-groups
#define TAPS 25
#define NPIX (NB * IMG)
#define RSTRIP 5                 // output rows per block (55 = 5*11, exact)
#define NSTRIP (HW / RSTRIP)     // 11
#define NWG (NB * NSTRIP)        // 1408 blocks
#define SROWS (RSTRIP + 4)       // 9 staged rows (halo +-2)
#define GCHUNK 4                 // active groups staged per pass
#define SLOTG 32                 // per-group slot capacity (>=25, mult of 8)
#define NXCD 8
#define BITEMS (RSTRIP * HW * GROUPS)  // 6600 f4 items per block
#define STAGEN (SROWS * HW)      // 495 staged pixels

typedef float v4f __attribute__((ext_vector_type(4)));

// ---- workspace ----
// float4 wslot[24][SLOTG] : compacted nonzero-tap weights per group (pad=0)  12288 B
// int2   dslot[24][SLOTG] : {dh+2, dw} per slot (pad: {2,0} w/ zero weight)   6144 B
// int    tapflag[24]      : group has any nonzero tap
// int    gact[24]         : compacted active-group list
// int    nga, nspad       : #active groups; max slots (padded to 8)

__global__ void repack_kernel(const float* __restrict__ k,
                              float4* __restrict__ wslot,
                              int2* __restrict__ dslot,
                              int* __restrict__ tapflag,
                              int* __restrict__ gact,
                              int* __restrict__ nga,
                              int* __restrict__ nspad) {
    __shared__ int s_ns[GROUPS];
    int g = threadIdx.x;
    if (g < GROUPS) {
        int ns = 0;
        for (int tap = 0; tap < TAPS; ++tap) {
            float w0 = k[(4 * g + 0) * TAPS + tap];
            float w1 = k[(4 * g + 1) * TAPS + tap];
            float w2 = k[(4 * g + 2) * TAPS + tap];
            float w3 = k[(4 * g + 3) * TAPS + tap];
            if (w0 != 0.f || w1 != 0.f || w2 != 0.f || w3 != 0.f) {
                int dh = tap / 5 - 2, dw = tap % 5 - 2;
                wslot[g * SLOTG + ns] = make_float4(w0, w1, w2, w3);
                dslot[g * SLOTG + ns] = make_int2(dh + 2, dw);
                ++ns;
            }
        }
        for (int s = ns; s < SLOTG; ++s) {           // pads: weight 0 -> contribute 0
            wslot[g * SLOTG + s] = make_float4(0.f, 0.f, 0.f, 0.f);
            dslot[g * SLOTG + s] = make_int2(2, 0);  // center, always valid
        }
        tapflag[g] = (ns > 0) ? 1 : 0;
        s_ns[g] = ns;
    }
    __syncthreads();
    if (threadIdx.x == 0) {
        int na = 0, m = 0;
        for (int gg = 0; gg < GROUPS; ++gg)
            if (s_ns[gg] > 0) { gact[na++] = gg; m = m > s_ns[gg] ? m : s_ns[gg]; }
        *nga = na;
        *nspad = (m + 7) & ~7;
    }
}

// ---- tiled kernel: h-strip per block, active-channel halo tile in LDS ----
__global__ __launch_bounds__(256) void tiled_kernel(const float* __restrict__ x,
                                                    const float4* __restrict__ wslot,
                                                    const int2* __restrict__ dslot,
                                                    const int* __restrict__ tapflag,
                                                    const int* __restrict__ gact,
                                                    const int* __restrict__ p_nga,
                                                    const int* __restrict__ p_nspad,
                                                    float* __restrict__ out) {
    __shared__ v4f s_x[STAGEN * GCHUNK];      // 9x55x4 f4 = 31680 B (halo tile)
    __shared__ float4 s_w[GCHUNK * SLOTG];    // 2048 B
    __shared__ int2 s_d[GCHUNK * SLOTG];      // 1024 B
    __shared__ int s_gaofg[GROUPS];           // group -> chunk-local idx or -1
    __shared__ int s_act[GROUPS];             // group active anywhere

    // Bijective chunked XCD swizzle (1408 % 8 == 0).
    const int q = NWG / NXCD, r = NWG % NXCD;
    int xcd = blockIdx.x & (NXCD - 1);
    int bidx = blockIdx.x >> 3;
    int swz = (xcd < r ? xcd * (q + 1) : r * (q + 1) + (xcd - r) * q) + bidx;

    const int n = swz / NSTRIP;
    const int strip = swz % NSTRIP;
    const int h0 = strip * RSTRIP;
    const int tid = threadIdx.x;
    const int nga = *p_nga;
    const int nsb = (*p_nspad) >> 3;          // slot batches of 8
    const int base_f4 = (n * IMG + h0 * HW) * GROUPS;
    const v4f* x4 = (const v4f*)x;
    v4f* o4 = (v4f*)out;

    int nchunk = (nga + GCHUNK - 1) / GCHUNK;
    if (nchunk < 1) nchunk = 1;               // nga==0 -> one pure-copy pass

    for (int c = 0; c < nchunk; ++c) {
        const int c0 = c * GCHUNK;
        int cn = nga - c0;
        if (cn > GCHUNK) cn = GCHUNK;
        if (cn < 0) cn = 0;

        if (tid < GROUPS) { s_gaofg[tid] = -1; s_act[tid] = tapflag[tid]; }
        __syncthreads();                       // init before scattered set
        if (tid < cn) s_gaofg[gact[c0 + tid]] = tid;
        // stage slot tables for this chunk
        for (int i = tid; i < cn * SLOTG; i += 256) {
            int ci = i / SLOTG, s = i - ci * SLOTG;
            int gg = gact[c0 + ci];
            s_w[ci * SLOTG + s] = wslot[gg * SLOTG + s];
            s_d[ci * SLOTG + s] = dslot[gg * SLOTG + s];
        }
        // stage x halo tile (coalesced stream; out-of-image rows -> zeros)
        const int stcnt = STAGEN * cn;
        const int wcn = HW * cn;
        for (int i = tid; i < stcnt; i += 256) {
            int srow = i / wcn;
            int rem2 = i - srow * wcn;
            int pix = rem2 / cn;
            int ci = rem2 - pix * cn;
            int h = h0 - 2 + srow;
            v4f v = {0.f, 0.f, 0.f, 0.f};
            if ((unsigned)h < (unsigned)HW)
                v = x4[(n * IMG + h * HW + pix) * GROUPS + gact[c0 + ci]];
            s_x[(srow * HW + pix) * GCHUNK + ci] = v;
        }
        __syncthreads();

        // compute: linear f4 items over the strip (dense coalesced load+store)
        for (int i = tid; i < BITEMS; i += 256) {
            int pixrel = i / GROUPS;          // magic-mul
            int gout = i - pixrel * GROUPS;
            v4f acc = x4[base_f4 + i];        // residual
            int gidx = s_gaofg[gout];
            if (gidx >= 0) {
                int rr = pixrel / HW;
                int pix = pixrel - rr * HW;
#pragma unroll 1
                for (int sb = 0; sb < nsb; ++sb) {
#pragma unroll
                    for (int si = 0; si < 8; ++si) {
                        int s = sb * 8 + si;
                        int2 d = s_d[gidx * SLOTG + s];
                        int srow = rr + d.x;              // d.x = dh+2, in [0,8]
                        int pix2 = pix + d.y;
                        bool valid = (unsigned)pix2 < (unsigned)HW;
                        float sc = valid ? 1.f : 0.f;
                        int p2 = valid ? pix2 : 0;
                        v4f xv = s_x[(srow * HW + p2) * GCHUNK + gidx];
                        float4 wv = s_w[gidx * SLOTG + s];
                        acc.x += (wv.x * sc) * xv.x;
                        acc.y += (wv.y * sc) * xv.y;
                        acc.z += (wv.z * sc) * xv.z;
                        acc.w += (wv.w * sc) * xv.w;
                    }
                }
            }
            // chunk 0 stores its own active items + all inactive items;
            // later chunks store only their items (single-chunk: stores all).
            bool dostore = (gidx >= 0) || (c == 0 && !s_act[gout]);
            if (dostore)
                __builtin_nontemporal_store(acc, &o4[base_f4 + i]);
        }
        if (c + 1 < nchunk) __syncthreads();   // before s_x reuse
    }
}

// ---- Fallback (ws too small): monolithic, reads raw k — correctness only ----
__global__ __launch_bounds__(256) void fallback_kernel(const float* __restrict__ x,
                                                       const float* __restrict__ kraw,
                                                       float* __restrict__ out) {
    int t = blockIdx.x * 256 + threadIdx.x;
    if (t >= NPIX * GROUPS) return;
    int g = t % GROUPS;
    int pixel = t / GROUPS;
    int rem = pixel % IMG;
    int h = rem / HW;
    int w = rem - h * HW;
    int base = pixel * CH + g * 4;
    const float4 xc = *reinterpret_cast<const float4*>(x + base);
    float4 acc = make_float4(xc.x, xc.y, xc.z, xc.w);
#pragma unroll
    for (int dh = -2; dh <= 2; ++dh)
#pragma unroll
        for (int dw = -2; dw <= 2; ++dw) {
            const int tap = (dh + 2) * 5 + (dw + 2);
            const bool valid = ((unsigned)(h + dh) < (unsigned)HW) &
                               ((unsigned)(w + dw) < (unsigned)HW);
            const float vs = valid ? 1.0f : 0.0f;
            const int off = valid ? (dh * HW * CH + dw * CH) : 0;
            const float4 xv = *reinterpret_cast<const float4*>(x + base + off);
            acc.x += (kraw[(g * 4 + 0) * TAPS + tap] * vs) * xv.x;
            acc.y += (kraw[(g * 4 + 1) * TAPS + tap] * vs) * xv.y;
            acc.z += (kraw[(g * 4 + 2) * TAPS + tap] * vs) * xv.z;
            acc.w += (kraw[(g * 4 + 3) * TAPS + tap] * vs) * xv.w;
        }
    *reinterpret_cast<float4*>(out + base) = acc;
}

extern "C" void kernel_launch(void* const* d_in, const int* in_sizes, int n_in,
                              void* d_out, int out_size, void* d_ws, size_t ws_size,
                              hipStream_t stream) {
    const float* x = (const float*)d_in[0];
    const float* k = (const float*)d_in[1];
    float* out = (float*)d_out;

    const size_t sz_wslot = (size_t)GROUPS * SLOTG * sizeof(float4);   // 12288
    const size_t sz_dslot = (size_t)GROUPS * SLOTG * sizeof(int2);     // 6144
    const size_t sz_flag = GROUPS * sizeof(int);
    const size_t sz_gact = GROUPS * sizeof(int);
    const size_t ws_need = sz_wslot + sz_dslot + sz_flag + sz_gact + 2 * sizeof(int);

    if (ws_size >= ws_need) {
        char* p = (char*)d_ws;
        float4* wslot = (float4*)p;  p += sz_wslot;
        int2* dslot = (int2*)p;      p += sz_dslot;
        int* tapflag = (int*)p;      p += sz_flag;
        int* gact = (int*)p;         p += sz_gact;
        int* nga = (int*)p;          p += sizeof(int);
        int* nspad = (int*)p;

        repack_kernel<<<1, 64, 0, stream>>>(k, wslot, dslot, tapflag, gact, nga, nspad);
        tiled_kernel<<<NWG, 256, 0, stream>>>(x, wslot, dslot, tapflag, gact,
                                              nga, nspad, out);
    } else {
        const int blocks = (NPIX * GROUPS) / 256;
        fallback_kernel<<<blocks, 256, 0, stream>>>(x, k, out);
    }
}